// Round 2
// baseline (29.811 us; speedup 1.0000x reference)
//
#include <hip/hip_runtime.h>
#include <hip/hip_bf16.h>

// loss = N * sum(x*x) - sum_d (colsum_d)^2, x is (256, D=100000) fp32 row-major.
// One streaming pass. Block = 256 threads = 32 float4-columns x 8 row-groups
// (32 rows each). 782 blocks -> ~3 blocks/CU all co-resident, every wave has
// identical work (balanced). unroll 16 + nontemporal 16B loads for deep MLP.
// LDS reduce across row groups; one float atomicAdd per block into d_out.

#define N_ROWS 256
#define CPB 32   // float4-columns per block
#define RG 8     // row groups per block
#define RPG 32   // rows per group (RG * RPG == N_ROWS)

typedef float f32x4 __attribute__((ext_vector_type(4)));

__global__ __launch_bounds__(256) void tpc_loss_kernel(
    const float* __restrict__ x, float* __restrict__ out, int D4, int D) {
  const int c = threadIdx.x & (CPB - 1);   // column within tile, 0..31
  const int g = threadIdx.x >> 5;          // row group, 0..7
  const long col4 = (long)blockIdx.x * CPB + c;

  f32x4 s = {0.f, 0.f, 0.f, 0.f};
  float q = 0.f;

  if (col4 < D4) {
    const float* p = x + (size_t)g * RPG * D + (size_t)col4 * 4;
#pragma unroll 16
    for (int r = 0; r < RPG; ++r) {
      f32x4 v = __builtin_nontemporal_load(
          reinterpret_cast<const f32x4*>(p + (size_t)r * D));
      s += v;
      q += v.x * v.x + v.y * v.y + v.z * v.z + v.w * v.w;
    }
  }

  // Reduce q across each 64-lane wave, then across the 4 waves via LDS.
#pragma unroll
  for (int off = 32; off > 0; off >>= 1) q += __shfl_down(q, off, 64);

  __shared__ f32x4 sh_s[RG][CPB];
  __shared__ float sh_q[4];
  sh_s[g][c] = s;
  if ((threadIdx.x & 63) == 0) sh_q[threadIdx.x >> 6] = q;
  __syncthreads();

  if (threadIdx.x < CPB) {
    // Thread t sums its column across the 8 row groups, then squares.
    f32x4 t = sh_s[0][threadIdx.x];
#pragma unroll
    for (int i = 1; i < RG; ++i) t += sh_s[i][threadIdx.x];
    float ssq = t.x * t.x + t.y * t.y + t.z * t.z + t.w * t.w;
    // Reduce ssq across lanes 0..31 (lanes >=32 of wave 0 are inactive but
    // shuffle width 64 with zero contribution from them is avoided by using
    // width-32 butterflies entirely within lanes 0..31).
#pragma unroll
    for (int off = 16; off > 0; off >>= 1) ssq += __shfl_down(ssq, off, 64);
    if (threadIdx.x == 0) {
      float qtot = sh_q[0] + sh_q[1] + sh_q[2] + sh_q[3];
      atomicAdd(out, (float)N_ROWS * qtot - ssq);
    }
  }
}

extern "C" void kernel_launch(void* const* d_in, const int* in_sizes, int n_in,
                              void* d_out, int out_size, void* d_ws, size_t ws_size,
                              hipStream_t stream) {
  const float* x = (const float*)d_in[0];
  float* out = (float*)d_out;
  const int total = in_sizes[0];
  const int D = total / N_ROWS;   // 100000
  const int D4 = D / 4;           // 25000

  hipMemsetAsync(d_out, 0, sizeof(float) * out_size, stream);

  const int blocks = (D4 + CPB - 1) / CPB;  // 782
  tpc_loss_kernel<<<blocks, 256, 0, stream>>>(x, out, D4, D);
}

// Round 3
// 28.102 us; speedup vs baseline: 1.0608x; 1.0608x over previous
//
#include <hip/hip_runtime.h>
#include <hip/hip_bf16.h>

// loss = N * sum(x*x) - sum_d (colsum_d)^2, x is (256, D=100000) fp32 row-major.
// Balance-first design: 256 blocks (one per CU) x 1024 threads (16 waves).
// Block b owns contiguous float4-columns [D4*b/256, D4*(b+1)/256) -> 97 or 98
// columns (1% imbalance vs 24% whole-block quantization of R1/R2).
// Thread = (rowgroup g 0..7, col-lane c 0..127); 32 rows each, float4 loads.
// LDS reduce -> one atomicAdd per block.

#define N_ROWS 256
#define NBLK 256
#define CLANES 128
#define RG 8
#define RPG 32

typedef float f32x4 __attribute__((ext_vector_type(4)));

__global__ __launch_bounds__(1024) void tpc_loss_kernel(
    const float* __restrict__ x, float* __restrict__ out, int D4, int D) {
  const int c = threadIdx.x & (CLANES - 1);  // 0..127
  const int g = threadIdx.x >> 7;            // 0..7
  const int c0 = (int)(((long)D4 * blockIdx.x) >> 8);
  const int c1 = (int)(((long)D4 * (blockIdx.x + 1)) >> 8);
  const int ncols = c1 - c0;                 // 97 or 98

  f32x4 s = {0.f, 0.f, 0.f, 0.f};
  float q = 0.f;

  if (c < ncols) {
    const float* p = x + (size_t)g * RPG * D + (size_t)(c0 + c) * 4;
#pragma unroll 16
    for (int r = 0; r < RPG; ++r) {
      f32x4 v = *reinterpret_cast<const f32x4*>(p + (size_t)r * D);
      s += v;
      q += v.x * v.x + v.y * v.y + v.z * v.z + v.w * v.w;
    }
  }

  // Per-wave reduce of q (16 waves).
#pragma unroll
  for (int off = 32; off > 0; off >>= 1) q += __shfl_down(q, off, 64);

  __shared__ f32x4 sh_s[RG][CLANES];  // 16 KB
  __shared__ float sh_q[16];
  sh_s[g][c] = s;                         // inactive cols write zeros
  if ((threadIdx.x & 63) == 0) sh_q[threadIdx.x >> 6] = q;
  __syncthreads();

  // Single-wave epilogue: lane l handles columns l and l+64.
  if (threadIdx.x < 64) {
    const int l = threadIdx.x;
    float ssq = 0.f;
#pragma unroll
    for (int half = 0; half < 2; ++half) {
      const int cc = l + half * 64;
      f32x4 t = sh_s[0][cc];
#pragma unroll
      for (int i = 1; i < RG; ++i) t += sh_s[i][cc];
      ssq += t.x * t.x + t.y * t.y + t.z * t.z + t.w * t.w;
    }
    float qw = (l < 16) ? sh_q[l] : 0.f;
#pragma unroll
    for (int off = 32; off > 0; off >>= 1) {
      ssq += __shfl_down(ssq, off, 64);
      qw  += __shfl_down(qw, off, 64);
    }
    if (l == 0) atomicAdd(out, (float)N_ROWS * qw - ssq);
  }
}

extern "C" void kernel_launch(void* const* d_in, const int* in_sizes, int n_in,
                              void* d_out, int out_size, void* d_ws, size_t ws_size,
                              hipStream_t stream) {
  const float* x = (const float*)d_in[0];
  float* out = (float*)d_out;
  const int total = in_sizes[0];
  const int D = total / N_ROWS;   // 100000
  const int D4 = D / 4;           // 25000

  hipMemsetAsync(d_out, 0, sizeof(float) * out_size, stream);
  tpc_loss_kernel<<<NBLK, 1024, 0, stream>>>(x, out, D4, D);
}